// Round 5
// baseline (355.884 us; speedup 1.0000x reference)
//
#include <hip/hip_runtime.h>
#include <hip/hip_bf16.h>
#include <hip/hip_cooperative_groups.h>

namespace cg = cooperative_groups;

// SAGEConv: N=10000 nodes, E=640000 edges, in_feat=128, out_feat=256.
// Inputs: h fp32 [10000,128], src/dst int32 [640000], W fp32 [256,256], b fp32 [256].
// Output fp32 [10000,256].
//
// Primary path: ONE cooperative kernel, GRID=256 (1 block/CU — co-resident under
// any occupancy accounting; round 4's GRID=512 launch was rejected, silently).
// Fallback path (if hipLaunchCooperativeKernel errors): round-3 multi-kernel
// pipeline. Decision is deterministic -> same work every call.
//
// Phases (grid.sync between):
//   A: blocks 0..127: LDS histogram of dst (5000-edge range) -> ghist
//      blocks 128..255: h fp32 -> bf16 copy hb32 + self half of A32
//   B: column-exclusive-scan of ghist -> per-block bases + cnt
//   C: block 0: exclusive scan of cnt -> CSR offs
//   D: blocks 0..127: re-walk edge range, LDS cursors, scatter src ids
//   E: wave per node (1024 waves x ~10 nodes): bf16 gather mean -> A32 mean half
//   F: MFMA bf16 GEMM tiles: out = [h | h_N] @ W + b (fp32 accum/out)
#define NN 10000
#define NE 640000
#define MPAD 10048   // 157 * 64
#define HB 128       // histogram blocks
#define EPB 5000     // edges per histogram block (NE / HB)
#define GRID 256     // 1 block/CU
#define NTILE 628    // 157 * 4 gemm tiles

typedef __attribute__((ext_vector_type(8))) short bf16x8;
typedef __attribute__((ext_vector_type(4))) float f32x4;

__device__ __forceinline__ unsigned packbf(float x, float y) {
  __hip_bfloat16 a = __float2bfloat16(x);
  __hip_bfloat16 c = __float2bfloat16(y);
  unsigned short ua = __builtin_bit_cast(unsigned short, a);
  unsigned short uc = __builtin_bit_cast(unsigned short, c);
  return (unsigned)ua | ((unsigned)uc << 16);
}
__device__ __forceinline__ float blo(unsigned u) { return __uint_as_float(u << 16); }
__device__ __forceinline__ float bhi(unsigned u) { return __uint_as_float(u & 0xffff0000u); }

// ---------- shared phase bodies (used by coop kernel AND fallback kernels) ----
__device__ __forceinline__ void do_hist(const int* __restrict__ dst,
                                        int* __restrict__ ghist, int* lh, int blk,
                                        int t) {
  for (int i = t; i < 10016; i += 256) lh[i] = 0;
  __syncthreads();
  int beg = blk * EPB;
  for (int e = t; e < EPB; e += 256) atomicAdd(&lh[dst[beg + e]], 1);
  __syncthreads();
  for (int i = t; i < NN; i += 256) ghist[blk * NN + i] = lh[i];
}

__device__ __forceinline__ void do_convert(const float* __restrict__ h,
                                           unsigned* __restrict__ hb32,
                                           unsigned* __restrict__ A32, int tid,
                                           int stride) {
  for (int j = tid; j < NN * 64; j += stride) {
    float2 v = ((const float2*)h)[j];
    unsigned p = packbf(v.x, v.y);
    hb32[j] = p;
    A32[(size_t)(j >> 6) * 128 + (j & 63)] = p;  // self features 0..127
  }
}

__device__ __forceinline__ void do_colscan(int* __restrict__ ghist,
                                           int* __restrict__ cnt, int v) {
  if (v >= NN) return;
  int s = 0;
#pragma unroll 4
  for (int b2 = 0; b2 < HB; b2++) {
    int x = ghist[b2 * NN + v];
    ghist[b2 * NN + v] = s;
    s += x;
  }
  cnt[v] = s;
}

// 256-thread exclusive scan of 10000 counts -> offs (single block).
__device__ __forceinline__ void do_scan256(const int* __restrict__ cnt,
                                           int* __restrict__ offs, int* lh, int t) {
  int base0 = t * 40;
  int s = 0;
#pragma unroll 8
  for (int i = 0; i < 40; i++) {
    int idx = base0 + i;
    s += (idx < NN) ? cnt[idx] : 0;
  }
  lh[t] = s;
  __syncthreads();
  for (int off = 1; off < 256; off <<= 1) {  // Hillis-Steele inclusive
    int add = (t >= off) ? lh[t - off] : 0;
    __syncthreads();
    lh[t] += add;
    __syncthreads();
  }
  int run = (t == 0) ? 0 : lh[t - 1];
  for (int i = 0; i < 40; i++) {
    int idx = base0 + i;
    if (idx < NN) {
      offs[idx] = run;
      run += cnt[idx];
    }
  }
  if (t == 255) offs[NN] = lh[255];  // = NE
}

__device__ __forceinline__ void do_scatter(const int* __restrict__ src,
                                           const int* __restrict__ dst,
                                           const int* __restrict__ offs,
                                           const int* __restrict__ ghist,
                                           int* __restrict__ esrc, int* lh, int blk,
                                           int t) {
  for (int i = t; i < NN; i += 256) lh[i] = offs[i] + ghist[blk * NN + i];
  __syncthreads();
  int beg = blk * EPB;
  for (int e = t; e < EPB; e += 256) {
    int d = dst[beg + e];
    int sv = src[beg + e];
    int p = atomicAdd(&lh[d], 1);
    esrc[p] = sv;
  }
}

__device__ __forceinline__ void do_aggregate(const unsigned* __restrict__ hb32,
                                             const int* __restrict__ offs,
                                             const int* __restrict__ esrc,
                                             unsigned* __restrict__ A32, int wave,
                                             int lane, int stride) {
  for (int node = wave; node < NN; node += stride) {
    int beg = offs[node], end = offs[node + 1];
    float a0 = 0.f, a1 = 0.f;
    int e = beg;
    for (; e + 7 < end; e += 8) {  // 8-wide for memory-level parallelism
      int s0 = esrc[e], s1 = esrc[e + 1], s2 = esrc[e + 2], s3 = esrc[e + 3];
      int s4 = esrc[e + 4], s5 = esrc[e + 5], s6 = esrc[e + 6], s7 = esrc[e + 7];
      unsigned u0 = hb32[s0 * 64 + lane], u1 = hb32[s1 * 64 + lane];
      unsigned u2 = hb32[s2 * 64 + lane], u3 = hb32[s3 * 64 + lane];
      unsigned u4 = hb32[s4 * 64 + lane], u5 = hb32[s5 * 64 + lane];
      unsigned u6 = hb32[s6 * 64 + lane], u7 = hb32[s7 * 64 + lane];
      a0 += (blo(u0) + blo(u1)) + (blo(u2) + blo(u3)) +
            ((blo(u4) + blo(u5)) + (blo(u6) + blo(u7)));
      a1 += (bhi(u0) + bhi(u1)) + (bhi(u2) + bhi(u3)) +
            ((bhi(u4) + bhi(u5)) + (bhi(u6) + bhi(u7)));
    }
    for (; e < end; e++) {
      unsigned u = hb32[esrc[e] * 64 + lane];
      a0 += blo(u);
      a1 += bhi(u);
    }
    int deg = end - beg;
    float inv = (deg > 0) ? 1.f / (float)deg : 0.f;
    A32[(size_t)node * 128 + 64 + lane] = packbf(a0 * inv, a1 * inv);
  }
}

__device__ __forceinline__ void do_gemm_tile(const unsigned* __restrict__ A32,
                                             const float* __restrict__ W,
                                             const float* __restrict__ bias,
                                             float* __restrict__ out,
                                             unsigned short (*As)[264], int bm,
                                             int bn, int t) {
#pragma unroll
  for (int i = 0; i < 8; i++) {  // stage 64 rows x 256 bf16 (32KB), 16B/thread
    int q = t + i * 256;
    int row = q >> 5, c = q & 31;
    int gr = bm * 64 + row;
    if (gr > NN - 1) gr = NN - 1;  // clamp (out-store guards m)
    uint4 v = *(const uint4*)(A32 + (size_t)gr * 128 + c * 4);
    *(uint4*)(&As[row][c * 8]) = v;
  }
  int w = t >> 6, l = t & 63, lm = l & 15, kb = l >> 4;
  int col = bn * 64 + w * 16 + lm;
  bf16x8 bfr[8];  // B fragment: B[k = ks*32 + kb*8 + j][col], fp32->bf16
#pragma unroll
  for (int ks = 0; ks < 8; ks++) {
#pragma unroll
    for (int j = 0; j < 8; j++) {
      float wv2 = W[(ks * 32 + kb * 8 + j) * 256 + col];
      bfr[ks][j] = (short)__builtin_bit_cast(unsigned short, __float2bfloat16(wv2));
    }
  }
  __syncthreads();
  f32x4 acc[4];
#pragma unroll
  for (int r = 0; r < 4; r++) acc[r] = (f32x4){0.f, 0.f, 0.f, 0.f};
#pragma unroll
  for (int ks = 0; ks < 8; ks++) {
#pragma unroll
    for (int r = 0; r < 4; r++) {
      uint4 araw = *(const uint4*)(&As[r * 16 + lm][ks * 32 + kb * 8]);
      bf16x8 af = __builtin_bit_cast(bf16x8, araw);
      acc[r] = __builtin_amdgcn_mfma_f32_16x16x32_bf16(af, bfr[ks], acc[r], 0, 0, 0);
    }
  }
  float biasf = bias[col];
#pragma unroll
  for (int r = 0; r < 4; r++) {
    int mbase = bm * 64 + r * 16 + kb * 4;  // C/D: row=(lane>>4)*4+reg, col=lane&15
#pragma unroll
    for (int reg = 0; reg < 4; reg++) {
      int m = mbase + reg;
      if (m < NN) out[(size_t)m * 256 + col] = acc[r][reg] + biasf;
    }
  }
}

// ------------------------------- cooperative kernel --------------------------
__global__ __launch_bounds__(256, 2) void k_all(
    const float* __restrict__ h, const int* __restrict__ src,
    const int* __restrict__ dst, const float* __restrict__ W,
    const float* __restrict__ bias, float* __restrict__ out,
    int* __restrict__ offs, int* __restrict__ cnt, int* __restrict__ esrc,
    int* __restrict__ ghist, unsigned* __restrict__ hb32,
    unsigned* __restrict__ A32) {
  cg::grid_group grid = cg::this_grid();
  __shared__ __align__(16) int lh[10016];  // hist / scan / cursors / GEMM A-tile
  int t = threadIdx.x;
  int blk = blockIdx.x;

  if (blk < HB)
    do_hist(dst, ghist, lh, blk, t);
  else
    do_convert(h, hb32, A32, (blk - HB) * 256 + t, (GRID - HB) * 256);
  grid.sync();

  do_colscan(ghist, cnt, blk * 256 + t);
  grid.sync();

  if (blk == 0) do_scan256(cnt, offs, lh, t);
  grid.sync();

  if (blk < HB) do_scatter(src, dst, offs, ghist, esrc, lh, blk, t);
  grid.sync();

  do_aggregate(hb32, offs, esrc, A32, blk * 4 + (t >> 6), t & 63, GRID * 4);
  grid.sync();

  unsigned short(*As)[264] = (unsigned short(*)[264])lh;
  for (int tile = blk; tile < NTILE; tile += GRID) {
    __syncthreads();  // protect LDS reuse across phases / tiles
    do_gemm_tile(A32, W, bias, out, As, tile >> 2, tile & 3, t);
  }
}

// ------------------------------- fallback kernels ----------------------------
__global__ __launch_bounds__(256) void kf_histconv(const float* __restrict__ h,
                                                   const int* __restrict__ dst,
                                                   int* __restrict__ ghist,
                                                   unsigned* __restrict__ hb32,
                                                   unsigned* __restrict__ A32) {
  __shared__ int lh[10016];
  int t = threadIdx.x, blk = blockIdx.x;
  if (blk < HB)
    do_hist(dst, ghist, lh, blk, t);
  else
    do_convert(h, hb32, A32, (blk - HB) * 256 + t, 256 * 256);  // grid 384
}

__global__ void kf_colscan(int* __restrict__ ghist, int* __restrict__ cnt) {
  do_colscan(ghist, cnt, blockIdx.x * 256 + threadIdx.x);
}

__global__ __launch_bounds__(256) void kf_scan(const int* __restrict__ cnt,
                                               int* __restrict__ offs) {
  __shared__ int lh[256];
  do_scan256(cnt, offs, lh, threadIdx.x);
}

__global__ __launch_bounds__(256) void kf_scatter(const int* __restrict__ src,
                                                  const int* __restrict__ dst,
                                                  const int* __restrict__ offs,
                                                  const int* __restrict__ ghist,
                                                  int* __restrict__ esrc) {
  __shared__ int lh[10016];
  do_scatter(src, dst, offs, ghist, esrc, lh, blockIdx.x, threadIdx.x);
}

__global__ void kf_aggregate(const unsigned* __restrict__ hb32,
                             const int* __restrict__ offs,
                             const int* __restrict__ esrc,
                             unsigned* __restrict__ A32) {
  do_aggregate(hb32, offs, esrc, A32, blockIdx.x * 4 + (threadIdx.x >> 6),
               threadIdx.x & 63, NN);
}

__global__ __launch_bounds__(256) void kf_gemm(const unsigned* __restrict__ A32,
                                               const float* __restrict__ W,
                                               const float* __restrict__ bias,
                                               float* __restrict__ out) {
  __shared__ __align__(16) unsigned short As[64][264];
  int tile = blockIdx.x;
  do_gemm_tile(A32, W, bias, out, As, tile >> 2, tile & 3, threadIdx.x);
}

extern "C" void kernel_launch(void* const* d_in, const int* in_sizes, int n_in,
                              void* d_out, int out_size, void* d_ws, size_t ws_size,
                              hipStream_t stream) {
  const float* h = (const float*)d_in[0];
  const int* src = (const int*)d_in[1];
  const int* dst = (const int*)d_in[2];
  const float* W = (const float*)d_in[3];
  const float* b = (const float*)d_in[4];
  float* out = (float*)d_out;

  char* ws = (char*)d_ws;
  // ws layout (~15.5 MB, 16B-aligned segments):
  int* offs = (int*)(ws + 0);                    // 10001 ints
  int* cnt = (int*)(ws + 40192);                 // 10000 ints
  int* esrc = (int*)(ws + 80384);                // 640000 ints      -> 2640384
  int* ghist = (int*)(ws + 2640384);             // 128*10000 ints   -> 7760384
  unsigned* hb32 = (unsigned*)(ws + 7760384);    // 10000*64 dwords  -> 10320384
  unsigned* A32 = (unsigned*)(ws + 10320384);    // MPAD*128 dwords (bf16 concat)

  void* args[] = {(void*)&h,    (void*)&src,   (void*)&dst,  (void*)&W,
                  (void*)&b,    (void*)&out,   (void*)&offs, (void*)&cnt,
                  (void*)&esrc, (void*)&ghist, (void*)&hb32, (void*)&A32};
  hipError_t err = hipLaunchCooperativeKernel((const void*)k_all, dim3(GRID),
                                              dim3(256), args, 0, stream);
  if (err != hipSuccess) {
    // Deterministic fallback: round-3-style multi-kernel pipeline.
    kf_histconv<<<384, 256, 0, stream>>>(h, dst, ghist, hb32, A32);
    kf_colscan<<<40, 256, 0, stream>>>(ghist, cnt);
    kf_scan<<<1, 256, 0, stream>>>(cnt, offs);
    kf_scatter<<<HB, 256, 0, stream>>>(src, dst, offs, ghist, esrc);
    kf_aggregate<<<2500, 256, 0, stream>>>(hb32, offs, esrc, A32);
    kf_gemm<<<NTILE, 256, 0, stream>>>(A32, W, b, out);
  }
}